// Round 2
// 457.462 us; speedup vs baseline: 1.0069x; 1.0069x over previous
//
#include <hip/hip_runtime.h>
#include <hip/hip_bf16.h>
#include <stdint.h>

// Problem constants (from reference)
#define M_DIM 8192              // 4*2048 batch*seq rows
#define N_DIM 4096              // out_features
#define K_DIM 4096              // in_features
#define NOG   4096              // num out groups (out_group=1)
#define NIG   512               // num in groups (in_group=8)

typedef __bf16 bf16;
typedef __attribute__((ext_vector_type(8))) __bf16 bf16x8;   // 4 VGPRs — MFMA A/B frag
typedef __attribute__((ext_vector_type(4))) float f32x4;     // MFMA C/D frag

// Tiled bf16 layout for both GEMM operands ("chunk order"):
//   tile(g, h) = rows [g*16,(g+1)*16) x cols [h*32,(h+1)*32)
//   stored as 64 consecutive 16-B chunks, chunk index c = kblk*16 + row
//   (kblk = 8-elem block within the 32 cols, row = row within group).
//   tile base (in chunks) = (g * (K_DIM/32) + h) * 64.
// GEMM staging then reads 1024 CONTIGUOUS bytes per gload16 (lane l -> chunk l)
// and LDS receives fragment-read order -> zero bank conflicts (measured 0).

// ---------------------------------------------------------------------------
// async global->LDS, 16 B per lane. LDS dest is wave-uniform base + lane*16.
__device__ __forceinline__ void gload16(const void* g, void* lds) {
    __builtin_amdgcn_global_load_lds(
        (__attribute__((address_space(1))) void*)g,
        (__attribute__((address_space(3))) void*)lds,
        16 /*size*/, 0 /*offset*/, 0 /*aux*/);
}

// ---------------------------------------------------------------------------
// Kernel 1: fp32 -> bf16 convert + transpose into chunk-order tiles.
// (unchanged — isolating the GEMM schedule change)
__global__ __launch_bounds__(256) void k_convert_tile(const float* __restrict__ in,
                                                      bf16* __restrict__ out) {
    __shared__ __align__(16) bf16 tile[256 * 8];   // 4 KB = 256 chunks
    const int t   = threadIdx.x;
    const int g   = blockIdx.y;          // row group (16 rows)
    const int h0  = blockIdx.x * 4;      // first 32-col half of the 4 we cover
    const int row = t >> 4;
    const int cc  = t & 15;              // 8-elem column chunk within 128 cols
    const float4* p = (const float4*)(in + (size_t)(g * 16 + row) * K_DIM
                                         + h0 * 32 + cc * 8);
    float4 a = p[0], b = p[1];
    bf16x8 v;
    v[0] = (bf16)a.x; v[1] = (bf16)a.y; v[2] = (bf16)a.z; v[3] = (bf16)a.w;
    v[4] = (bf16)b.x; v[5] = (bf16)b.y; v[6] = (bf16)b.z; v[7] = (bf16)b.w;
    const int widx = (cc >> 2) * 64 + (cc & 3) * 16 + row;
    ((bf16x8*)tile)[widx] = v;
    __syncthreads();
    bf16x8 o = ((bf16x8*)tile)[t];
    ((bf16x8*)out)[((size_t)g * 128 + h0) * 64 + t] = o;   // contiguous 4 KB store
}

// ---------------------------------------------------------------------------
// Kernel 2: AQLM dequant straight into chunk-order tiles. (unchanged)
__global__ __launch_bounds__(256) void k_dequant_tile(const int* __restrict__ codes,
                                                      const float* __restrict__ cb,
                                                      const float* __restrict__ scales,
                                                      bf16* __restrict__ w) {
    const int t    = threadIdx.x;
    const int gB   = blockIdx.y;           // out-feature group (16 rows)
    const int h0   = blockIdx.x * 4;       // first 32-col half
    const int hl   = t >> 6;               // half within block (0..3)
    const int kblk = (t >> 4) & 3;         // in-group within half
    const int row  = t & 15;               // out-feature within group
    const int o    = gB * 16 + row;
    const int iG   = blockIdx.x * 16 + hl * 4 + kblk;
    unsigned code = (unsigned)codes[o * NIG + iG];
    float s = scales[o];
    const float4* e = (const float4*)(cb + (size_t)code * 8);
    float4 e0 = e[0], e1 = e[1];
    bf16x8 v;
    v[0] = (bf16)(e0.x * s); v[1] = (bf16)(e0.y * s);
    v[2] = (bf16)(e0.z * s); v[3] = (bf16)(e0.w * s);
    v[4] = (bf16)(e1.x * s); v[5] = (bf16)(e1.y * s);
    v[6] = (bf16)(e1.z * s); v[7] = (bf16)(e1.w * s);
    ((bf16x8*)w)[((size_t)gB * 128 + h0) * 64 + t] = v;
}

// ---------------------------------------------------------------------------
// Kernel 3: C[m,n] = sum_k A[m,k]*B[n,k] + bias[n]  on chunk-order tiles.
//
// Schedule (T3+T4+T5): BM=BN=256, BK=64, 8 waves (2M x 4N), wave tile
// 128x64. LDS double-buffered (128 KB). K-loop split into 2 phases per
// K-step (one 32-wide k-slice each). Per phase:
//   {12 ds_read_b128 of current slice}  {4 gload16 staging slice s+2 into
//   the OTHER buffer}  s_waitcnt vmcnt(4)  s_barrier  lgkmcnt(0)+sched_bar
//   setprio(1) 32xMFMA setprio(0)  s_barrier
// vmcnt is COUNTED (4 = the just-issued stage), never 0 in the main loop,
// so prefetch loads stay in flight across barriers. Hazard chain:
//  - phase p reads slice s_p, staged at phase p-2; phase p-1's vmcnt(4)
//    (own wave) + its barrier (all waves) guarantee arrival.
//  - stages always target the buffer NOT being read this K-step; the
//    end-of-step barrier (reads drained by lgkmcnt before MFMA) precedes
//    any overwrite of the just-read buffer.
//  - all ds_reads/gloads are pinned between "memory"-clobber asm fences,
//    so the compiler cannot migrate them across the counted waits.
// Tail: phases whose prefetch slice would be >127 simply skip staging
// (wave-uniform branch; vmcnt(4) still trivially satisfiable -> no hang).
#define BM 256
#define BN 256
#define BK 64
#define KSTEPS (K_DIM / BK)

__device__ __forceinline__ void gemm_phase(
    const bf16* __restrict__ AsR, const bf16* __restrict__ BsR,  // read buffer bases
    bf16* __restrict__ AsW, bf16* __restrict__ BsW,              // wave's write bases (other buf)
    const bf16* paw0, const bf16* paw1, const bf16* pbw0, const bf16* pbw1,
    int gA0, int gB0, int lane, const int h, int ss,
    f32x4 (&acc)[8][4])
{
    // Fragment reads: 64 consecutive 16-B chunks per half -> conflict-free.
    bf16x8 af[8], bq[4];
    #pragma unroll
    for (int m = 0; m < 8; ++m)
        af[m] = *(const bf16x8*)(AsR + (size_t)(gA0 + m) * 1024 + h * 512 + lane * 8);
    #pragma unroll
    for (int j = 0; j < 4; ++j)
        bq[j] = *(const bf16x8*)(BsR + (size_t)(gB0 + j) * 1024 + h * 512 + lane * 8);

    // Stage slice ss (half h of K-step ss>>1) into the other buffer.
    if (ss < 128) {   // wave-uniform: skipped only in the loop tail
        gload16(paw0 + (size_t)ss * 512, AsW + h * 512);
        gload16(paw1 + (size_t)ss * 512, AsW + 1024 + h * 512);
        gload16(pbw0 + (size_t)ss * 512, BsW + h * 512);
        gload16(pbw1 + (size_t)ss * 512, BsW + 1024 + h * 512);
    }

    // Counted wait: drains everything older than the 4 loads just issued,
    // i.e. the slice the NEXT phase will read. Never 0 in the main loop.
    asm volatile("s_waitcnt vmcnt(4)" ::: "memory");
    __builtin_amdgcn_s_barrier();
    asm volatile("s_waitcnt lgkmcnt(0)" ::: "memory");
    __builtin_amdgcn_sched_barrier(0);   // rule 18: keep MFMAs below the wait

    __builtin_amdgcn_s_setprio(1);
    #pragma unroll
    for (int i = 0; i < 8; ++i)
        #pragma unroll
        for (int j = 0; j < 4; ++j)
            acc[i][j] = __builtin_amdgcn_mfma_f32_16x16x32_bf16(
                af[i], bq[j], acc[i][j], 0, 0, 0);
    __builtin_amdgcn_s_setprio(0);
    __builtin_amdgcn_s_barrier();
}

__global__ __launch_bounds__(512, 2) void k_gemm_tiled(
    const bf16* __restrict__ A,      // chunk-order tiled [512 groups][128 halves]
    const bf16* __restrict__ B,      // chunk-order tiled [256 groups][128 halves]
    const float* __restrict__ bias,  // [N_DIM]
    float* __restrict__ C)           // [M_DIM, N_DIM] row-major
{
    // Double-buffered LDS: [buf][group*1024 + half*512 + elem], 16 groups each.
    __shared__ __align__(16) bf16 As[2][16 * 1024];   // 64 KB
    __shared__ __align__(16) bf16 Bs[2][16 * 1024];   // 64 KB

    const int tid  = threadIdx.x;
    const int wave = tid >> 6;         // 0..7
    const int lane = tid & 63;
    const int quad = lane >> 4;        // 0..3
    const int l16  = lane & 15;

    const int bn0 = blockIdx.x * BN;
    const int bm0 = blockIdx.y * BM;
    const int wm  = (wave >> 2) * 128; // wave's 128x64 subtile
    const int wn  = (wave & 3) * 64;
    const int gA0 = (wave >> 2) * 8;   // first A group this wave's frags use
    const int gB0 = (wave & 3) * 4;    // first B group

    // Staging sources: wave w owns A groups {w*2, w*2+1} and B groups
    // {w*2, w*2+1}; lane l fetches chunk l. Group stride = 8192 chunks.
    const bf16* paw0 = A + ((size_t)(blockIdx.y * 16 + wave * 2 + 0) * 8192 + lane) * 8;
    const bf16* paw1 = A + ((size_t)(blockIdx.y * 16 + wave * 2 + 1) * 8192 + lane) * 8;
    const bf16* pbw0 = B + ((size_t)(blockIdx.x * 16 + wave * 2 + 0) * 8192 + lane) * 8;
    const bf16* pbw1 = B + ((size_t)(blockIdx.x * 16 + wave * 2 + 1) * 8192 + lane) * 8;

    bf16* As0w = &As[0][wave * 2048];  // wave's 2 A groups in buf0
    bf16* As1w = &As[1][wave * 2048];
    bf16* Bs0w = &Bs[0][wave * 2048];
    bf16* Bs1w = &Bs[1][wave * 2048];

    // Prologue: slices 0,1 (K-step 0) -> buf0. Queue order [s0 x4, s1 x4].
    gload16(paw0,       As0w);        gload16(paw1,       As0w + 1024);
    gload16(pbw0,       Bs0w);        gload16(pbw1,       Bs0w + 1024);
    gload16(paw0 + 512, As0w + 512);  gload16(paw1 + 512, As0w + 1536);
    gload16(pbw0 + 512, Bs0w + 512);  gload16(pbw1 + 512, Bs0w + 1536);
    asm volatile("s_waitcnt vmcnt(4)" ::: "memory");   // slice 0 ready
    __builtin_amdgcn_s_barrier();

    f32x4 acc[8][4] = {};

    const bf16* AsR0 = &As[0][0]; const bf16* BsR0 = &Bs[0][0];
    const bf16* AsR1 = &As[1][0]; const bf16* BsR1 = &Bs[1][0];

    for (int ks = 0; ks < KSTEPS; ks += 2) {
        const int s0 = ks * 2;
        // K-step ks: read buf0, stage slices s0+2,s0+3 -> buf1
        gemm_phase(AsR0, BsR0, As1w, Bs1w, paw0, paw1, pbw0, pbw1,
                   gA0, gB0, lane, 0, s0 + 2, acc);
        gemm_phase(AsR0, BsR0, As1w, Bs1w, paw0, paw1, pbw0, pbw1,
                   gA0, gB0, lane, 1, s0 + 3, acc);
        // K-step ks+1: read buf1, stage slices s0+4,s0+5 -> buf0
        gemm_phase(AsR1, BsR1, As0w, Bs0w, paw0, paw1, pbw0, pbw1,
                   gA0, gB0, lane, 0, s0 + 4, acc);
        gemm_phase(AsR1, BsR1, As0w, Bs0w, paw0, paw1, pbw0, pbw1,
                   gA0, gB0, lane, 1, s0 + 5, acc);
    }

    // Epilogue: C/D layout col = lane&15, row = quad*4 + reg  [m89/m91-verified]
    #pragma unroll
    for (int j = 0; j < 4; ++j) {
        const int gn = bn0 + wn + j * 16 + l16;
        const float bz = bias[gn];
        #pragma unroll
        for (int i = 0; i < 8; ++i) {
            float* cp = C + (size_t)(bm0 + wm + i * 16 + quad * 4) * N_DIM + gn;
            #pragma unroll
            for (int r = 0; r < 4; ++r)
                cp[(size_t)r * N_DIM] = acc[i][j][r] + bz;
        }
    }
}

// ---------------------------------------------------------------------------
extern "C" void kernel_launch(void* const* d_in, const int* in_sizes, int n_in,
                              void* d_out, int out_size, void* d_ws, size_t ws_size,
                              hipStream_t stream) {
    const float* input     = (const float*)d_in[0];   // [4,2048,4096]
    const int*   codes     = (const int*)d_in[1];     // [4096,512,1]
    const float* codebooks = (const float*)d_in[2];   // [1,65536,1,8]
    const float* scales    = (const float*)d_in[3];   // [4096]
    const float* bias      = (const float*)d_in[4];   // [4096]
    float* out = (float*)d_out;                        // [4,2048,4096]

    // Workspace: A_tiled (67.1 MB) then W_tiled (33.5 MB); both fully written
    // before the GEMM reads them, so the 0xAA poison is irrelevant.
    bf16* Abf = (bf16*)d_ws;
    bf16* Wbf = (bf16*)((char*)d_ws + (size_t)M_DIM * K_DIM * sizeof(bf16));

    (void)in_sizes; (void)n_in; (void)out_size; (void)ws_size;

    // 1) activation fp32 -> bf16, tiled  (grid: 32 col-quads x 512 row-groups)
    {
        dim3 g(K_DIM / 128, M_DIM / 16);
        k_convert_tile<<<g, 256, 0, stream>>>(input, Abf);
    }
    // 2) dequantize W -> bf16, tiled  (grid: 32 col-quads x 256 row-groups)
    {
        dim3 g(K_DIM / 128, NOG / 16);
        k_dequant_tile<<<g, 256, 0, stream>>>(codes, codebooks, scales, Wbf);
    }
    // 3) NT GEMM + bias on tiled operands, 8-wave double-buffered schedule
    {
        dim3 g(N_DIM / BN, M_DIM / BM);   // (16, 32) = 512 blocks
        k_gemm_tiled<<<g, 512, 0, stream>>>(Abf, Wbf, bias, out);
    }
}